// Round 16
// baseline (186.552 us; speedup 1.0000x reference)
//
#include <hip/hip_runtime.h>
#include <hip/hip_bf16.h>

#define BB 4
#define SS 1024
#define NPTS 16384
#define DD 128
#define EPSF 1e-6f

// ws layout (float element offsets)
#define OFF_COL    448      // 64   colsum of attn over S, per (b,j)
#define OFF_IDX    70144    // 65536 (int)
#define OFF_ATTN   135680   // 65536
#define OFF_G      205312   // 524288 (kp4: (x,y,z,kk) per point, 262144 floats)
#define OFF_WVT    729600   // 16384 (Wv transposed)

__device__ __forceinline__ unsigned long long shflxor_u64(unsigned long long v, int m) {
  unsigned int lo = (unsigned int)(v & 0xffffffffull);
  unsigned int hi = (unsigned int)(v >> 32);
  lo = (unsigned int)__shfl_xor((int)lo, m, 64);
  hi = (unsigned int)__shfl_xor((int)hi, m, 64);
  return ((unsigned long long)hi << 32) | (unsigned long long)lo;
}

__device__ __forceinline__ unsigned long long u64min(unsigned long long a, unsigned long long b) {
  return a < b ? a : b;
}

__device__ __forceinline__ unsigned long long wavemin_u64(unsigned long long v) {
#pragma unroll
  for (int m = 1; m <= 32; m <<= 1) v = u64min(v, shflxor_u64(v, m));
  return v;
}

// ---------- K1: tiny prep -- kp4 pack + WVT transpose + COL zero ----------
// The 34MB rowsums pass is gone (qsum/ksum fused into k_knn). kp4 pack uses
// identical FP ops to the verified version.
__global__ __launch_bounds__(256) void k_pre(const float* __restrict__ kpos,
                                             const float* __restrict__ Wv,
                                             float* __restrict__ ws) {
  const int tid = threadIdx.x;
  const int bid = (int)blockIdx.x;
  if (bid < 128) {
    if (tid < 128) ws[OFF_WVT + bid * DD + tid] = Wv[tid * DD + bid];
  } else if (bid == 128) {
    if (tid < 64) ws[OFF_COL + tid] = 0.f;
  }
  const int pid = bid * 256 + tid;
  if (pid < BB * NPTS) {
    const float x = kpos[pid * 3 + 0], y = kpos[pid * 3 + 1], z = kpos[pid * 3 + 2];
    const float kk = __fadd_rn(__fadd_rn(__fmul_rn(x, x), __fmul_rn(y, y)), __fmul_rn(z, z));
    ((float4*)(ws + OFF_G))[pid] = make_float4(x, y, z, kk);
  }
}

// ---------- K2: fused KNN + colsums + qsum/ksum + scores + softmax ----------
// R16 = R15's VERIFIED scan/selection byte-identical (kp4 path, shifted
// filter, tight O(1) cutoff, cap 48, cand[8] merge) + the fusion arm of R13
// tested IN ISOLATION (R14 proved direct-kpos was the R13/R14 bug; the
// fusion was never individually tested -- bf16 output rounding masked it):
//  - per-block colsums cq/ck/W2S + bias sums (arithmetic-equivalent to
//    k_pre's: two 64-row halves, part[j]+part[128+j])
//  - per-wave qsum = dot(qf_row, cq) + sum(bq)
//  - epilogue ksum for the 16 selected rows on the fly (float4 x8 per lane
//    over the pe lane-split, reduced over replicas)
// Score sums reorder by ~1e-5 (threshold 1.9e-3, current absmax 2.4e-4).
#define FORQ(X) X(0) X(1) X(2) X(3) X(4) X(5) X(6) X(7)

__global__ __launch_bounds__(512, 6) void k_knn(const float* __restrict__ qf,
                                                const float* __restrict__ kf,
                                                const float* __restrict__ qpos,
                                                const float* __restrict__ kpos,
                                                const float* __restrict__ Wq,
                                                const float* __restrict__ bq,
                                                const float* __restrict__ Wk,
                                                const float* __restrict__ bk,
                                                const float* __restrict__ W1,
                                                const float* __restrict__ b1,
                                                const float* __restrict__ W2,
                                                const float* __restrict__ b2,
                                                float* __restrict__ ws) {
  __shared__ unsigned long long cbuf[8][8][48];  // [query][wave][slot] 24 KB
  __shared__ float pmins[8][8][64];              // [wave][query][lane] 16 KB
  __shared__ int cnts[8][8];
  __shared__ __align__(16) float cq_s[128];
  __shared__ __align__(16) float ck_s[128];
  __shared__ __align__(16) float w2s_s[128];
  __shared__ float part[256];
  __shared__ float scl_s[3];
  const int tid = threadIdx.x;
  const int w = tid >> 6, l = tid & 63;
  const int qbase = (int)blockIdx.x * 8;         // linear mapping
  const int b = qbase >> 10;

  // ===== init: colsums (k_pre-equivalent op order), biases =====
  {
    float sq = 0.f, sk = 0.f, s2 = 0.f;
    const int jj = tid & 127, hh = (tid >> 7) & 1;
    if (tid < 256) {
      const int r0 = hh * 64;
      for (int r = r0; r < r0 + 64; ++r) {
        sq += Wq[r * DD + jj];
        sk += Wk[r * DD + jj];
        s2 += W2[r * DD + jj];
      }
    }
    if (tid < 256) part[tid] = sq;
    __syncthreads();
    if (tid < 128) cq_s[tid] = part[tid] + part[128 + tid];
    __syncthreads();
    if (tid < 256) part[tid] = sk;
    __syncthreads();
    if (tid < 128) ck_s[tid] = part[tid] + part[128 + tid];
    __syncthreads();
    if (tid < 256) part[tid] = s2;
    __syncthreads();
    if (tid < 128) w2s_s[tid] = part[tid] + part[128 + tid];
    if (tid < 64) {
      float a0 = bq[tid] + bq[tid + 64];
      float a1 = bk[tid] + bk[tid + 64];
      float a2 = b2[tid] + b2[tid + 64];
#pragma unroll
      for (int m = 1; m <= 32; m <<= 1) {
        a0 += __shfl_xor(a0, m, 64);
        a1 += __shfl_xor(a1, m, 64);
        a2 += __shfl_xor(a2, m, 64);
      }
      if (tid == 0) { scl_s[0] = a0; scl_s[1] = a1; scl_s[2] = a2; }
    }
    __syncthreads();
  }

  // per-wave qsum for query qbase + w
  float qsum_w;
  {
    const float* qrow = qf + (size_t)(qbase + w) * DD;
    float s = fmaf(qrow[l + 64], cq_s[l + 64], __fmul_rn(qrow[l], cq_s[l]));
#pragma unroll
    for (int m = 1; m <= 32; m <<= 1) s += __shfl_xor(s, m, 64);
    qsum_w = s + scl_s[0];
  }

  const float4* kp4 = (const float4*)(ws + OFF_G) + (size_t)b * NPTS;
  const float* kp = kpos + (size_t)b * NPTS * 3;

#define LOADQ(i) \
  const float qx##i = qpos[(size_t)(qbase + i) * 3 + 0]; \
  const float qy##i = qpos[(size_t)(qbase + i) * 3 + 1]; \
  const float qz##i = qpos[(size_t)(qbase + i) * 3 + 2]; \
  const float qq##i = __fadd_rn(__fadd_rn(__fmul_rn(qx##i, qx##i), __fmul_rn(qy##i, qy##i)), __fmul_rn(qz##i, qz##i));
  FORQ(LOADQ)
#undef LOADQ

  const int sbase = w * 2048;

  // ---- pass 1 (FULL): per-lane min of shifted filter s = kk - 2*dotA ----
#define DECLMN(i) float mn##i = 3.4e38f;
  FORQ(DECLMN)
#undef DECLMN
  {
    const float4* p0 = kp4 + sbase + l;
    float4 c0 = p0[0], c1 = p0[64], c2 = p0[128], c3 = p0[192];
    const float4* nx = p0 + 256;
#define P1Q(i, cc) { \
      const float dA = fmaf(qx##i, (cc).x, fmaf(qy##i, (cc).y, __fmul_rn(qz##i, (cc).z))); \
      const float sF = fmaf(-2.0f, dA, (cc).w); \
      mn##i = fminf(mn##i, sF); }
#define P1_PT(cc, RELOAD) { \
      P1Q(0, cc) P1Q(1, cc) P1Q(2, cc) P1Q(3, cc) \
      P1Q(4, cc) P1Q(5, cc) P1Q(6, cc) P1Q(7, cc) \
      cc = RELOAD; }
    for (int t = 0; t < 8; ++t) {
      P1_PT(c0, nx[0])
      P1_PT(c1, nx[64])
      P1_PT(c2, nx[128])
      P1_PT(c3, nx[192])
      nx += 256;
    }
#undef P1_PT
  }
#define STMN(i) pmins[w][i][l] = mn##i;
  FORQ(STMN)
#undef STMN
  __syncthreads();

  // ---- cutoffs (shifted space): per query, max over 16 groups of
  //      min-over-1024-points; groups g = l&15 partition all 16384 ----
#define CUTQ(i) float cut##i; { \
    float m = pmins[0][i][l]; \
    m = fminf(m, pmins[1][i][l]); m = fminf(m, pmins[2][i][l]); \
    m = fminf(m, pmins[3][i][l]); m = fminf(m, pmins[4][i][l]); \
    m = fminf(m, pmins[5][i][l]); m = fminf(m, pmins[6][i][l]); \
    m = fminf(m, pmins[7][i][l]); \
    m = fminf(m, __shfl_xor(m, 16, 64)); \
    m = fminf(m, __shfl_xor(m, 32, 64)); \
    m = fmaxf(m, __shfl_xor(m, 1, 64)); \
    m = fmaxf(m, __shfl_xor(m, 2, 64)); \
    m = fmaxf(m, __shfl_xor(m, 4, 64)); \
    m = fmaxf(m, __shfl_xor(m, 8, 64)); \
    cut##i = m + 2e-5f; }
  FORQ(CUTQ)
#undef CUTQ

  // ---- pass 2 (FULL): shifted filter, exact d2 key for survivors ----
#define DECLCNT(i) int cnt##i = 0;
  FORQ(DECLCNT)
#undef DECLCNT
  {
    const float4* p0 = kp4 + sbase + l;
    float4 c0 = p0[0], c1 = p0[64], c2 = p0[128], c3 = p0[192];
    const float4* nx = p0 + 256;
    int p = sbase + l;
#define P2Q(i, cc, pp) { \
      const float dA = fmaf(qx##i, (cc).x, fmaf(qy##i, (cc).y, __fmul_rn(qz##i, (cc).z))); \
      const float sF = fmaf(-2.0f, dA, (cc).w); \
      const bool pred = (sF <= cut##i); \
      const unsigned long long mask = __ballot(pred); \
      if (mask) { \
        if (pred) { \
          const float dotE = __fadd_rn(__fadd_rn(__fmul_rn(qz##i, (cc).z), __fmul_rn(qy##i, (cc).y)), __fmul_rn(qx##i, (cc).x)); \
          const float d2e = __fadd_rn(__fsub_rn(qq##i, __fmul_rn(2.0f, dotE)), (cc).w); \
          unsigned int u = __float_as_uint(d2e); \
          u ^= (unsigned int)((int)u >> 31) | 0x80000000u; \
          const int off = __builtin_amdgcn_mbcnt_hi((unsigned int)(mask >> 32), \
                          __builtin_amdgcn_mbcnt_lo((unsigned int)mask, 0)); \
          const int pos = cnt##i + off; \
          if (pos < 48) cbuf[i][w][pos] = ((unsigned long long)u << 32) | (unsigned int)(pp); \
        } \
        cnt##i += (int)__popcll(mask); \
      } }
#define P2_PT(cc, RELOAD, POFF) { \
      P2Q(0, cc, p + POFF) P2Q(1, cc, p + POFF) P2Q(2, cc, p + POFF) P2Q(3, cc, p + POFF) \
      P2Q(4, cc, p + POFF) P2Q(5, cc, p + POFF) P2Q(6, cc, p + POFF) P2Q(7, cc, p + POFF) \
      cc = RELOAD; }
    for (int t = 0; t < 8; ++t) {
      P2_PT(c0, nx[0], 0)
      P2_PT(c1, nx[64], 64)
      P2_PT(c2, nx[128], 128)
      P2_PT(c3, nx[192], 192)
      nx += 256;
      p += 256;
    }
#undef P2_PT
#undef P2Q
  }
#define STCNT(i) if (l == 0) cnts[i][w] = (cnt##i > 48 ? 48 : cnt##i);
  FORQ(STCNT)
#undef STCNT
  __syncthreads();

  // ---- merge + epilogue: wave w owns query qbase + w ----
  const int qi = w;
  const int q = qbase + qi;
  unsigned long long cand[8];
#pragma unroll
  for (int i = 0; i < 8; ++i) {
    const int cn = cnts[qi][i];
    cand[i] = (l < cn) ? cbuf[qi][i][l] : ~0ull;
  }
  unsigned long long lmin = cand[0]; int lpos = 0;
#pragma unroll
  for (int i = 1; i < 8; ++i) { if (cand[i] < lmin) { lmin = cand[i]; lpos = i; } }
  unsigned long long sel64 = 0;
  for (int r = 0; r < 16; ++r) {
    const unsigned long long m = wavemin_u64(lmin);
    if (l == r) sel64 = m;
    if (lmin == m) {
#pragma unroll
      for (int i = 0; i < 8; ++i) cand[i] = (lpos == i) ? ~0ull : cand[i];
      lmin = cand[0]; lpos = 0;
#pragma unroll
      for (int i = 1; i < 8; ++i) { if (cand[i] < lmin) { lmin = cand[i]; lpos = i; } }
    }
  }
  const int myidx = (int)(sel64 & 0xffffffffull);
  if (l < 16) ((int*)(ws + OFF_IDX))[q * 16 + l] = myidx;

  // scores: j = l&15 owns neighbor j; 4 replicas (l>>4) cover 32 channels
  // each of pe AND ksum (on-the-fly, fused).
  const float* qpw = qpos + (size_t)q * 3;
  const float gx = qpw[0], gy = qpw[1], gz = qpw[2];
  const int j = l & 15;
  const int pj = __shfl(myidx, j, 64);
  const float* kpj = kp + (size_t)pj * 3;
  const float rx = gx - kpj[0];
  const float ry = gy - kpj[1];
  const float rz = gz - kpj[2];
  const int i0 = (l >> 4) * 32;
  float pe = 0.f;
  for (int i = i0; i < i0 + 32; ++i) {
    float hh = fmaf(rx, W1[i * 3 + 0], fmaf(ry, W1[i * 3 + 1], fmaf(rz, W1[i * 3 + 2], b1[i])));
    hh = fmaxf(hh, 0.f);
    pe = fmaf(hh, w2s_s[i], pe);
  }
  float ks = 0.f;
  {
    const float4* k4 = (const float4*)(kf + (size_t)b * NPTS * DD + (size_t)pj * DD + i0);
    const float4* c4 = (const float4*)(ck_s + i0);
#pragma unroll
    for (int ii = 0; ii < 8; ++ii) {
      const float4 kv = k4[ii];
      const float4 cv = c4[ii];
      ks = fmaf(kv.x, cv.x, ks);
      ks = fmaf(kv.y, cv.y, ks);
      ks = fmaf(kv.z, cv.z, ks);
      ks = fmaf(kv.w, cv.w, ks);
    }
  }
  pe += __shfl_xor(pe, 16, 64);
  pe += __shfl_xor(pe, 32, 64);
  ks += __shfl_xor(ks, 16, 64);
  ks += __shfl_xor(ks, 32, 64);
  float score = qsum_w - (ks + scl_s[1]) + pe + scl_s[2];
  float mx = score;
  mx = fmaxf(mx, __shfl_xor(mx, 1, 64));
  mx = fmaxf(mx, __shfl_xor(mx, 2, 64));
  mx = fmaxf(mx, __shfl_xor(mx, 4, 64));
  mx = fmaxf(mx, __shfl_xor(mx, 8, 64));
  const float e = expf(score - mx);
  float se = e;
  se += __shfl_xor(se, 1, 64);
  se += __shfl_xor(se, 2, 64);
  se += __shfl_xor(se, 4, 64);
  se += __shfl_xor(se, 8, 64);
  const float attn = e / se;
  if (l < 16) {
    ws[OFF_ATTN + q * 16 + l] = attn;
    atomicAdd(&ws[OFF_COL + b * 16 + l], attn);
  }
}

// ---------- K3: fused gather + out (byte-identical to R15 pass) ----------
__global__ __launch_bounds__(256) void k_go(const float* __restrict__ kf,
                                            const float* __restrict__ bv,
                                            const float* __restrict__ ws,
                                            float* __restrict__ out) {
  __shared__ float xg[8 * 128];
  __shared__ float as_s[8];
  const int tid = threadIdx.x;
  const int w = tid >> 6, l = tid & 63;
  const int qbase = (int)blockIdx.x * 8;
  const int b = qbase >> 10;
  const float* kb = kf + (size_t)b * NPTS * DD;

#pragma unroll
  for (int u = 0; u < 2; ++u) {
    const int qi = w * 2 + u;
    const int q = qbase + qi;
    float a = 0.f;
    int pidx = 0;
    if (l < 16) {
      a = ws[OFF_ATTN + q * 16 + l] / (ws[OFF_COL + b * 16 + l] + EPSF);
      pidx = ((const int*)(ws + OFF_IDX))[q * 16 + l];
    }
    float asum = a;
    asum += __shfl_xor(asum, 1, 64);
    asum += __shfl_xor(asum, 2, 64);
    asum += __shfl_xor(asum, 4, 64);
    asum += __shfl_xor(asum, 8, 64);
    if (l == 0) as_s[qi] = asum;
    float acc0 = 0.f, acc1 = 0.f;
#pragma unroll
    for (int jj = 0; jj < 16; ++jj) {
      const float aj = __shfl(a, jj, 64);
      const int pj = __shfl(pidx, jj, 64);
      const float* row = kb + (size_t)pj * DD;
      acc0 = fmaf(aj, row[l], acc0);
      acc1 = fmaf(aj, row[64 + l], acc1);
    }
    xg[qi * 128 + l] = acc0;
    xg[qi * 128 + 64 + l] = acc1;
  }
  __syncthreads();

  const int o = tid & 127, rg = tid >> 7;  // rg 0..1, rows rg*4 .. rg*4+3
  const float bvo = bv[o];
  float acc[4];
#pragma unroll
  for (int r = 0; r < 4; ++r) acc[r] = as_s[rg * 4 + r] * bvo;
  for (int i = 0; i < DD; ++i) {
    const float wv = ws[OFF_WVT + i * DD + o];
#pragma unroll
    for (int r = 0; r < 4; ++r) acc[r] = fmaf(wv, xg[(rg * 4 + r) * 128 + i], acc[r]);
  }
#pragma unroll
  for (int r = 0; r < 4; ++r) out[(size_t)(qbase + rg * 4 + r) * DD + o] = acc[r];
}

extern "C" void kernel_launch(void* const* d_in, const int* in_sizes, int n_in,
                              void* d_out, int out_size, void* d_ws, size_t ws_size,
                              hipStream_t stream) {
  const float* qf   = (const float*)d_in[0];
  const float* kf   = (const float*)d_in[1];
  const float* qpos = (const float*)d_in[2];
  const float* kpos = (const float*)d_in[3];
  const float* Wq   = (const float*)d_in[4];
  const float* bq   = (const float*)d_in[5];
  const float* Wk   = (const float*)d_in[6];
  const float* bk   = (const float*)d_in[7];
  const float* Wv   = (const float*)d_in[8];
  const float* bv   = (const float*)d_in[9];
  const float* W1   = (const float*)d_in[10];
  const float* b1   = (const float*)d_in[11];
  const float* W2   = (const float*)d_in[12];
  const float* b2   = (const float*)d_in[13];
  float* ws  = (float*)d_ws;
  float* out = (float*)d_out;

  k_pre<<<256, 256, 0, stream>>>(kpos, Wv, ws);
  k_knn<<<512, 512, 0, stream>>>(qf, kf, qpos, kpos, Wq, bq, Wk, bk, W1, b1, W2, b2, ws);
  k_go<<<512, 256, 0, stream>>>(kf, bv, ws, out);
}

// Round 17
// 171.673 us; speedup vs baseline: 1.0867x; 1.0867x over previous
//
#include <hip/hip_runtime.h>
#include <hip/hip_bf16.h>

#define BB 4
#define SS 1024
#define NPTS 16384
#define DD 128
#define EPSF 1e-6f

// ws layout (float element offsets)
#define OFF_CQ     0        // 128  colsum(Wq)
#define OFF_CK     128      // 128  colsum(Wk)
#define OFF_W2S    256      // 128  colsum(W2)
#define OFF_SCL    384      // 8    [0]=sum(bq) [1]=sum(bk) [2]=sum(b2)
#define OFF_COL    448      // 64   colsum of attn over S, per (b,j)
#define OFF_IDX    70144    // 65536 (int)
#define OFF_ATTN   135680   // 65536
#define OFF_G      205312   // 524288 (kp4: (x,y,z,kk) per point, 262144 floats)
#define OFF_WVT    729600   // 16384 (Wv transposed)

__device__ __forceinline__ unsigned long long shflxor_u64(unsigned long long v, int m) {
  unsigned int lo = (unsigned int)(v & 0xffffffffull);
  unsigned int hi = (unsigned int)(v >> 32);
  lo = (unsigned int)__shfl_xor((int)lo, m, 64);
  hi = (unsigned int)__shfl_xor((int)hi, m, 64);
  return ((unsigned long long)hi << 32) | (unsigned long long)lo;
}

__device__ __forceinline__ unsigned long long u64min(unsigned long long a, unsigned long long b) {
  return a < b ? a : b;
}

__device__ __forceinline__ unsigned long long wavemin_u64(unsigned long long v) {
#pragma unroll
  for (int m = 1; m <= 32; m <<= 1) v = u64min(v, shflxor_u64(v, m));
  return v;
}

// ---------- K1: tiny prep -- kp4 pack + WVT + COL zero + ONE-TIME colsums ----------
// Colsum op order IDENTICAL to R16's verified init (two 64-row halves,
// part[j] + part[128+j]; bias via 64-lane shfl chain) so all downstream
// values are bit-identical; computed once (blocks 129/130) instead of
// redundantly per k_knn block (R16's regression: 98MB L2 + serialized init).
__global__ __launch_bounds__(256) void k_pre(const float* __restrict__ kpos,
                                             const float* __restrict__ Wv,
                                             const float* __restrict__ Wq,
                                             const float* __restrict__ bq,
                                             const float* __restrict__ Wk,
                                             const float* __restrict__ bk,
                                             const float* __restrict__ W2,
                                             const float* __restrict__ b2,
                                             float* __restrict__ ws) {
  const int tid = threadIdx.x;
  const int bid = (int)blockIdx.x;
  __shared__ float part[256];

  if (bid < 128) {
    if (tid < 128) ws[OFF_WVT + bid * DD + tid] = Wv[tid * DD + bid];
  } else if (bid == 128) {
    if (tid < 64) ws[OFF_COL + tid] = 0.f;
  } else if (bid == 129) {
    // cq, ck, scl[0], scl[1] -- R16 init op order
    const int jj = tid & 127, hh = (tid >> 7) & 1;
    const int r0 = hh * 64;
    float sq = 0.f, sk = 0.f;
    for (int r = r0; r < r0 + 64; ++r) {
      sq += Wq[r * DD + jj];
      sk += Wk[r * DD + jj];
    }
    part[tid] = sq;
    __syncthreads();
    if (tid < 128) ws[OFF_CQ + tid] = part[tid] + part[128 + tid];
    __syncthreads();
    part[tid] = sk;
    __syncthreads();
    if (tid < 128) ws[OFF_CK + tid] = part[tid] + part[128 + tid];
    if (tid < 64) {
      float a0 = bq[tid] + bq[tid + 64];
      float a1 = bk[tid] + bk[tid + 64];
#pragma unroll
      for (int m = 1; m <= 32; m <<= 1) {
        a0 += __shfl_xor(a0, m, 64);
        a1 += __shfl_xor(a1, m, 64);
      }
      if (tid == 0) { ws[OFF_SCL + 0] = a0; ws[OFF_SCL + 1] = a1; }
    }
  } else if (bid == 130) {
    // w2s, scl[2]
    const int jj = tid & 127, hh = (tid >> 7) & 1;
    const int r0 = hh * 64;
    float s2 = 0.f;
    for (int r = r0; r < r0 + 64; ++r) s2 += W2[r * DD + jj];
    part[tid] = s2;
    __syncthreads();
    if (tid < 128) ws[OFF_W2S + tid] = part[tid] + part[128 + tid];
    if (tid < 64) {
      float a2 = b2[tid] + b2[tid + 64];
#pragma unroll
      for (int m = 1; m <= 32; m <<= 1) a2 += __shfl_xor(a2, m, 64);
      if (tid == 0) ws[OFF_SCL + 2] = a2;
    }
  }
  const int pid = bid * 256 + tid;
  if (pid < BB * NPTS) {
    const float x = kpos[pid * 3 + 0], y = kpos[pid * 3 + 1], z = kpos[pid * 3 + 2];
    const float kk = __fadd_rn(__fadd_rn(__fmul_rn(x, x), __fmul_rn(y, y)), __fmul_rn(z, z));
    ((float4*)(ws + OFF_G))[pid] = make_float4(x, y, z, kk);
  }
}

// ---------- K2: fused KNN + qsum/ksum + scores + softmax + colsum ----------
// R17 = R16 (verified absmax 2.44e-4) with the per-block colsum recompute
// replaced by three 512B LDS fills from ws (one-time k_pre values,
// bit-identical). Scan/selection/qsum/ksum-epilogue byte-identical to R16.
#define FORQ(X) X(0) X(1) X(2) X(3) X(4) X(5) X(6) X(7)

__global__ __launch_bounds__(512, 6) void k_knn(const float* __restrict__ qf,
                                                const float* __restrict__ kf,
                                                const float* __restrict__ qpos,
                                                const float* __restrict__ kpos,
                                                const float* __restrict__ W1,
                                                const float* __restrict__ b1,
                                                float* __restrict__ ws) {
  __shared__ unsigned long long cbuf[8][8][48];  // [query][wave][slot] 24 KB
  __shared__ float pmins[8][8][64];              // [wave][query][lane] 16 KB
  __shared__ int cnts[8][8];
  __shared__ __align__(16) float cq_s[128];
  __shared__ __align__(16) float ck_s[128];
  __shared__ __align__(16) float w2s_s[128];
  __shared__ float scl_s[3];
  const int tid = threadIdx.x;
  const int w = tid >> 6, l = tid & 63;
  const int qbase = (int)blockIdx.x * 8;         // linear mapping
  const int b = qbase >> 10;

  // ===== init: load one-time colsums/biases from ws =====
  if (tid < 128) {
    cq_s[tid]  = ws[OFF_CQ + tid];
    ck_s[tid]  = ws[OFF_CK + tid];
    w2s_s[tid] = ws[OFF_W2S + tid];
  }
  if (tid < 3) scl_s[tid] = ws[OFF_SCL + tid];
  __syncthreads();

  // per-wave qsum for query qbase + w (R16 op order)
  float qsum_w;
  {
    const float* qrow = qf + (size_t)(qbase + w) * DD;
    float s = fmaf(qrow[l + 64], cq_s[l + 64], __fmul_rn(qrow[l], cq_s[l]));
#pragma unroll
    for (int m = 1; m <= 32; m <<= 1) s += __shfl_xor(s, m, 64);
    qsum_w = s + scl_s[0];
  }

  const float4* kp4 = (const float4*)(ws + OFF_G) + (size_t)b * NPTS;
  const float* kp = kpos + (size_t)b * NPTS * 3;

#define LOADQ(i) \
  const float qx##i = qpos[(size_t)(qbase + i) * 3 + 0]; \
  const float qy##i = qpos[(size_t)(qbase + i) * 3 + 1]; \
  const float qz##i = qpos[(size_t)(qbase + i) * 3 + 2]; \
  const float qq##i = __fadd_rn(__fadd_rn(__fmul_rn(qx##i, qx##i), __fmul_rn(qy##i, qy##i)), __fmul_rn(qz##i, qz##i));
  FORQ(LOADQ)
#undef LOADQ

  const int sbase = w * 2048;

  // ---- pass 1 (FULL): per-lane min of shifted filter s = kk - 2*dotA ----
#define DECLMN(i) float mn##i = 3.4e38f;
  FORQ(DECLMN)
#undef DECLMN
  {
    const float4* p0 = kp4 + sbase + l;
    float4 c0 = p0[0], c1 = p0[64], c2 = p0[128], c3 = p0[192];
    const float4* nx = p0 + 256;
#define P1Q(i, cc) { \
      const float dA = fmaf(qx##i, (cc).x, fmaf(qy##i, (cc).y, __fmul_rn(qz##i, (cc).z))); \
      const float sF = fmaf(-2.0f, dA, (cc).w); \
      mn##i = fminf(mn##i, sF); }
#define P1_PT(cc, RELOAD) { \
      P1Q(0, cc) P1Q(1, cc) P1Q(2, cc) P1Q(3, cc) \
      P1Q(4, cc) P1Q(5, cc) P1Q(6, cc) P1Q(7, cc) \
      cc = RELOAD; }
    for (int t = 0; t < 8; ++t) {
      P1_PT(c0, nx[0])
      P1_PT(c1, nx[64])
      P1_PT(c2, nx[128])
      P1_PT(c3, nx[192])
      nx += 256;
    }
#undef P1_PT
  }
#define STMN(i) pmins[w][i][l] = mn##i;
  FORQ(STMN)
#undef STMN
  __syncthreads();

  // ---- cutoffs (shifted space): per query, max over 16 groups of
  //      min-over-1024-points; groups g = l&15 partition all 16384 ----
#define CUTQ(i) float cut##i; { \
    float m = pmins[0][i][l]; \
    m = fminf(m, pmins[1][i][l]); m = fminf(m, pmins[2][i][l]); \
    m = fminf(m, pmins[3][i][l]); m = fminf(m, pmins[4][i][l]); \
    m = fminf(m, pmins[5][i][l]); m = fminf(m, pmins[6][i][l]); \
    m = fminf(m, pmins[7][i][l]); \
    m = fminf(m, __shfl_xor(m, 16, 64)); \
    m = fminf(m, __shfl_xor(m, 32, 64)); \
    m = fmaxf(m, __shfl_xor(m, 1, 64)); \
    m = fmaxf(m, __shfl_xor(m, 2, 64)); \
    m = fmaxf(m, __shfl_xor(m, 4, 64)); \
    m = fmaxf(m, __shfl_xor(m, 8, 64)); \
    cut##i = m + 2e-5f; }
  FORQ(CUTQ)
#undef CUTQ

  // ---- pass 2 (FULL): shifted filter, exact d2 key for survivors ----
#define DECLCNT(i) int cnt##i = 0;
  FORQ(DECLCNT)
#undef DECLCNT
  {
    const float4* p0 = kp4 + sbase + l;
    float4 c0 = p0[0], c1 = p0[64], c2 = p0[128], c3 = p0[192];
    const float4* nx = p0 + 256;
    int p = sbase + l;
#define P2Q(i, cc, pp) { \
      const float dA = fmaf(qx##i, (cc).x, fmaf(qy##i, (cc).y, __fmul_rn(qz##i, (cc).z))); \
      const float sF = fmaf(-2.0f, dA, (cc).w); \
      const bool pred = (sF <= cut##i); \
      const unsigned long long mask = __ballot(pred); \
      if (mask) { \
        if (pred) { \
          const float dotE = __fadd_rn(__fadd_rn(__fmul_rn(qz##i, (cc).z), __fmul_rn(qy##i, (cc).y)), __fmul_rn(qx##i, (cc).x)); \
          const float d2e = __fadd_rn(__fsub_rn(qq##i, __fmul_rn(2.0f, dotE)), (cc).w); \
          unsigned int u = __float_as_uint(d2e); \
          u ^= (unsigned int)((int)u >> 31) | 0x80000000u; \
          const int off = __builtin_amdgcn_mbcnt_hi((unsigned int)(mask >> 32), \
                          __builtin_amdgcn_mbcnt_lo((unsigned int)mask, 0)); \
          const int pos = cnt##i + off; \
          if (pos < 48) cbuf[i][w][pos] = ((unsigned long long)u << 32) | (unsigned int)(pp); \
        } \
        cnt##i += (int)__popcll(mask); \
      } }
#define P2_PT(cc, RELOAD, POFF) { \
      P2Q(0, cc, p + POFF) P2Q(1, cc, p + POFF) P2Q(2, cc, p + POFF) P2Q(3, cc, p + POFF) \
      P2Q(4, cc, p + POFF) P2Q(5, cc, p + POFF) P2Q(6, cc, p + POFF) P2Q(7, cc, p + POFF) \
      cc = RELOAD; }
    for (int t = 0; t < 8; ++t) {
      P2_PT(c0, nx[0], 0)
      P2_PT(c1, nx[64], 64)
      P2_PT(c2, nx[128], 128)
      P2_PT(c3, nx[192], 192)
      nx += 256;
      p += 256;
    }
#undef P2_PT
#undef P2Q
  }
#define STCNT(i) if (l == 0) cnts[i][w] = (cnt##i > 48 ? 48 : cnt##i);
  FORQ(STCNT)
#undef STCNT
  __syncthreads();

  // ---- merge + epilogue: wave w owns query qbase + w ----
  const int qi = w;
  const int q = qbase + qi;
  unsigned long long cand[8];
#pragma unroll
  for (int i = 0; i < 8; ++i) {
    const int cn = cnts[qi][i];
    cand[i] = (l < cn) ? cbuf[qi][i][l] : ~0ull;
  }
  unsigned long long lmin = cand[0]; int lpos = 0;
#pragma unroll
  for (int i = 1; i < 8; ++i) { if (cand[i] < lmin) { lmin = cand[i]; lpos = i; } }
  unsigned long long sel64 = 0;
  for (int r = 0; r < 16; ++r) {
    const unsigned long long m = wavemin_u64(lmin);
    if (l == r) sel64 = m;
    if (lmin == m) {
#pragma unroll
      for (int i = 0; i < 8; ++i) cand[i] = (lpos == i) ? ~0ull : cand[i];
      lmin = cand[0]; lpos = 0;
#pragma unroll
      for (int i = 1; i < 8; ++i) { if (cand[i] < lmin) { lmin = cand[i]; lpos = i; } }
    }
  }
  const int myidx = (int)(sel64 & 0xffffffffull);
  if (l < 16) ((int*)(ws + OFF_IDX))[q * 16 + l] = myidx;

  // scores: j = l&15 owns neighbor j; 4 replicas (l>>4) cover 32 channels
  // each of pe AND ksum (on-the-fly, fused -- R16 verified).
  const float* qpw = qpos + (size_t)q * 3;
  const float gx = qpw[0], gy = qpw[1], gz = qpw[2];
  const int j = l & 15;
  const int pj = __shfl(myidx, j, 64);
  const float* kpj = kp + (size_t)pj * 3;
  const float rx = gx - kpj[0];
  const float ry = gy - kpj[1];
  const float rz = gz - kpj[2];
  const int i0 = (l >> 4) * 32;
  float pe = 0.f;
  for (int i = i0; i < i0 + 32; ++i) {
    float hh = fmaf(rx, W1[i * 3 + 0], fmaf(ry, W1[i * 3 + 1], fmaf(rz, W1[i * 3 + 2], b1[i])));
    hh = fmaxf(hh, 0.f);
    pe = fmaf(hh, w2s_s[i], pe);
  }
  float ks = 0.f;
  {
    const float4* k4 = (const float4*)(kf + (size_t)b * NPTS * DD + (size_t)pj * DD + i0);
    const float4* c4 = (const float4*)(ck_s + i0);
#pragma unroll
    for (int ii = 0; ii < 8; ++ii) {
      const float4 kv = k4[ii];
      const float4 cv = c4[ii];
      ks = fmaf(kv.x, cv.x, ks);
      ks = fmaf(kv.y, cv.y, ks);
      ks = fmaf(kv.z, cv.z, ks);
      ks = fmaf(kv.w, cv.w, ks);
    }
  }
  pe += __shfl_xor(pe, 16, 64);
  pe += __shfl_xor(pe, 32, 64);
  ks += __shfl_xor(ks, 16, 64);
  ks += __shfl_xor(ks, 32, 64);
  float score = qsum_w - (ks + scl_s[1]) + pe + scl_s[2];
  float mx = score;
  mx = fmaxf(mx, __shfl_xor(mx, 1, 64));
  mx = fmaxf(mx, __shfl_xor(mx, 2, 64));
  mx = fmaxf(mx, __shfl_xor(mx, 4, 64));
  mx = fmaxf(mx, __shfl_xor(mx, 8, 64));
  const float e = expf(score - mx);
  float se = e;
  se += __shfl_xor(se, 1, 64);
  se += __shfl_xor(se, 2, 64);
  se += __shfl_xor(se, 4, 64);
  se += __shfl_xor(se, 8, 64);
  const float attn = e / se;
  if (l < 16) {
    ws[OFF_ATTN + q * 16 + l] = attn;
    atomicAdd(&ws[OFF_COL + b * 16 + l], attn);
  }
}

// ---------- K3: fused gather + out (byte-identical to R15/R16 pass) ----------
__global__ __launch_bounds__(256) void k_go(const float* __restrict__ kf,
                                            const float* __restrict__ bv,
                                            const float* __restrict__ ws,
                                            float* __restrict__ out) {
  __shared__ float xg[8 * 128];
  __shared__ float as_s[8];
  const int tid = threadIdx.x;
  const int w = tid >> 6, l = tid & 63;
  const int qbase = (int)blockIdx.x * 8;
  const int b = qbase >> 10;
  const float* kb = kf + (size_t)b * NPTS * DD;

#pragma unroll
  for (int u = 0; u < 2; ++u) {
    const int qi = w * 2 + u;
    const int q = qbase + qi;
    float a = 0.f;
    int pidx = 0;
    if (l < 16) {
      a = ws[OFF_ATTN + q * 16 + l] / (ws[OFF_COL + b * 16 + l] + EPSF);
      pidx = ((const int*)(ws + OFF_IDX))[q * 16 + l];
    }
    float asum = a;
    asum += __shfl_xor(asum, 1, 64);
    asum += __shfl_xor(asum, 2, 64);
    asum += __shfl_xor(asum, 4, 64);
    asum += __shfl_xor(asum, 8, 64);
    if (l == 0) as_s[qi] = asum;
    float acc0 = 0.f, acc1 = 0.f;
#pragma unroll
    for (int jj = 0; jj < 16; ++jj) {
      const float aj = __shfl(a, jj, 64);
      const int pj = __shfl(pidx, jj, 64);
      const float* row = kb + (size_t)pj * DD;
      acc0 = fmaf(aj, row[l], acc0);
      acc1 = fmaf(aj, row[64 + l], acc1);
    }
    xg[qi * 128 + l] = acc0;
    xg[qi * 128 + 64 + l] = acc1;
  }
  __syncthreads();

  const int o = tid & 127, rg = tid >> 7;  // rg 0..1, rows rg*4 .. rg*4+3
  const float bvo = bv[o];
  float acc[4];
#pragma unroll
  for (int r = 0; r < 4; ++r) acc[r] = as_s[rg * 4 + r] * bvo;
  for (int i = 0; i < DD; ++i) {
    const float wv = ws[OFF_WVT + i * DD + o];
#pragma unroll
    for (int r = 0; r < 4; ++r) acc[r] = fmaf(wv, xg[(rg * 4 + r) * 128 + i], acc[r]);
  }
#pragma unroll
  for (int r = 0; r < 4; ++r) out[(size_t)(qbase + rg * 4 + r) * DD + o] = acc[r];
}

extern "C" void kernel_launch(void* const* d_in, const int* in_sizes, int n_in,
                              void* d_out, int out_size, void* d_ws, size_t ws_size,
                              hipStream_t stream) {
  const float* qf   = (const float*)d_in[0];
  const float* kf   = (const float*)d_in[1];
  const float* qpos = (const float*)d_in[2];
  const float* kpos = (const float*)d_in[3];
  const float* Wq   = (const float*)d_in[4];
  const float* bq   = (const float*)d_in[5];
  const float* Wk   = (const float*)d_in[6];
  const float* bk   = (const float*)d_in[7];
  const float* Wv   = (const float*)d_in[8];
  const float* bv   = (const float*)d_in[9];
  const float* W1   = (const float*)d_in[10];
  const float* b1   = (const float*)d_in[11];
  const float* W2   = (const float*)d_in[12];
  const float* b2   = (const float*)d_in[13];
  float* ws  = (float*)d_ws;
  float* out = (float*)d_out;

  k_pre<<<256, 256, 0, stream>>>(kpos, Wv, Wq, bq, Wk, bk, W2, b2, ws);
  k_knn<<<512, 512, 0, stream>>>(qf, kf, qpos, kpos, W1, b1, ws);
  k_go<<<512, 256, 0, stream>>>(kf, bv, ws, out);
}

// Round 18
// 170.009 us; speedup vs baseline: 1.0973x; 1.0098x over previous
//
#include <hip/hip_runtime.h>
#include <hip/hip_bf16.h>

#define BB 4
#define SS 1024
#define NPTS 16384
#define DD 128
#define EPSF 1e-6f

// ws layout (float element offsets)
#define OFF_CQ     0        // 128  colsum(Wq)
#define OFF_CK     128      // 128  colsum(Wk)
#define OFF_W2S    256      // 128  colsum(W2)
#define OFF_SCL    384      // 8    [0]=sum(bq) [1]=sum(bk) [2]=sum(b2)
#define OFF_COL    448      // 64   colsum of attn over S, per (b,j)
#define OFF_IDX    70144    // 65536 (int)
#define OFF_ATTN   135680   // 65536
#define OFF_G      205312   // 524288 (kp4: (x,y,z,kk) per point, 262144 floats)
#define OFF_WVT    729600   // 16384 (Wv transposed)

__device__ __forceinline__ unsigned long long shflxor_u64(unsigned long long v, int m) {
  unsigned int lo = (unsigned int)(v & 0xffffffffull);
  unsigned int hi = (unsigned int)(v >> 32);
  lo = (unsigned int)__shfl_xor((int)lo, m, 64);
  hi = (unsigned int)__shfl_xor((int)hi, m, 64);
  return ((unsigned long long)hi << 32) | (unsigned long long)lo;
}

__device__ __forceinline__ unsigned long long u64min(unsigned long long a, unsigned long long b) {
  return a < b ? a : b;
}

__device__ __forceinline__ unsigned long long wavemin_u64(unsigned long long v) {
#pragma unroll
  for (int m = 1; m <= 32; m <<= 1) v = u64min(v, shflxor_u64(v, m));
  return v;
}

// ---------- K1: tiny prep -- kp4 pack + WVT + COL zero + one-time colsums ----------
// (byte-identical to R17 pass)
__global__ __launch_bounds__(256) void k_pre(const float* __restrict__ kpos,
                                             const float* __restrict__ Wv,
                                             const float* __restrict__ Wq,
                                             const float* __restrict__ bq,
                                             const float* __restrict__ Wk,
                                             const float* __restrict__ bk,
                                             const float* __restrict__ W2,
                                             const float* __restrict__ b2,
                                             float* __restrict__ ws) {
  const int tid = threadIdx.x;
  const int bid = (int)blockIdx.x;
  __shared__ float part[256];

  if (bid < 128) {
    if (tid < 128) ws[OFF_WVT + bid * DD + tid] = Wv[tid * DD + bid];
  } else if (bid == 128) {
    if (tid < 64) ws[OFF_COL + tid] = 0.f;
  } else if (bid == 129) {
    const int jj = tid & 127, hh = (tid >> 7) & 1;
    const int r0 = hh * 64;
    float sq = 0.f, sk = 0.f;
    for (int r = r0; r < r0 + 64; ++r) {
      sq += Wq[r * DD + jj];
      sk += Wk[r * DD + jj];
    }
    part[tid] = sq;
    __syncthreads();
    if (tid < 128) ws[OFF_CQ + tid] = part[tid] + part[128 + tid];
    __syncthreads();
    part[tid] = sk;
    __syncthreads();
    if (tid < 128) ws[OFF_CK + tid] = part[tid] + part[128 + tid];
    if (tid < 64) {
      float a0 = bq[tid] + bq[tid + 64];
      float a1 = bk[tid] + bk[tid + 64];
#pragma unroll
      for (int m = 1; m <= 32; m <<= 1) {
        a0 += __shfl_xor(a0, m, 64);
        a1 += __shfl_xor(a1, m, 64);
      }
      if (tid == 0) { ws[OFF_SCL + 0] = a0; ws[OFF_SCL + 1] = a1; }
    }
  } else if (bid == 130) {
    const int jj = tid & 127, hh = (tid >> 7) & 1;
    const int r0 = hh * 64;
    float s2 = 0.f;
    for (int r = r0; r < r0 + 64; ++r) s2 += W2[r * DD + jj];
    part[tid] = s2;
    __syncthreads();
    if (tid < 128) ws[OFF_W2S + tid] = part[tid] + part[128 + tid];
    if (tid < 64) {
      float a2 = b2[tid] + b2[tid + 64];
#pragma unroll
      for (int m = 1; m <= 32; m <<= 1) a2 += __shfl_xor(a2, m, 64);
      if (tid == 0) ws[OFF_SCL + 2] = a2;
    }
  }
  const int pid = bid * 256 + tid;
  if (pid < BB * NPTS) {
    const float x = kpos[pid * 3 + 0], y = kpos[pid * 3 + 1], z = kpos[pid * 3 + 2];
    const float kk = __fadd_rn(__fadd_rn(__fmul_rn(x, x), __fmul_rn(y, y)), __fmul_rn(z, z));
    ((float4*)(ws + OFF_G))[pid] = make_float4(x, y, z, kk);
  }
}

// ---------- K2: fused KNN + qsum/ksum + scores + softmax + colsum ----------
// (byte-identical to R17 pass)
#define FORQ(X) X(0) X(1) X(2) X(3) X(4) X(5) X(6) X(7)

__global__ __launch_bounds__(512, 6) void k_knn(const float* __restrict__ qf,
                                                const float* __restrict__ kf,
                                                const float* __restrict__ qpos,
                                                const float* __restrict__ kpos,
                                                const float* __restrict__ W1,
                                                const float* __restrict__ b1,
                                                float* __restrict__ ws) {
  __shared__ unsigned long long cbuf[8][8][48];  // [query][wave][slot] 24 KB
  __shared__ float pmins[8][8][64];              // [wave][query][lane] 16 KB
  __shared__ int cnts[8][8];
  __shared__ __align__(16) float cq_s[128];
  __shared__ __align__(16) float ck_s[128];
  __shared__ __align__(16) float w2s_s[128];
  __shared__ float scl_s[3];
  const int tid = threadIdx.x;
  const int w = tid >> 6, l = tid & 63;
  const int qbase = (int)blockIdx.x * 8;         // linear mapping
  const int b = qbase >> 10;

  // ===== init: load one-time colsums/biases from ws =====
  if (tid < 128) {
    cq_s[tid]  = ws[OFF_CQ + tid];
    ck_s[tid]  = ws[OFF_CK + tid];
    w2s_s[tid] = ws[OFF_W2S + tid];
  }
  if (tid < 3) scl_s[tid] = ws[OFF_SCL + tid];
  __syncthreads();

  // per-wave qsum for query qbase + w
  float qsum_w;
  {
    const float* qrow = qf + (size_t)(qbase + w) * DD;
    float s = fmaf(qrow[l + 64], cq_s[l + 64], __fmul_rn(qrow[l], cq_s[l]));
#pragma unroll
    for (int m = 1; m <= 32; m <<= 1) s += __shfl_xor(s, m, 64);
    qsum_w = s + scl_s[0];
  }

  const float4* kp4 = (const float4*)(ws + OFF_G) + (size_t)b * NPTS;
  const float* kp = kpos + (size_t)b * NPTS * 3;

#define LOADQ(i) \
  const float qx##i = qpos[(size_t)(qbase + i) * 3 + 0]; \
  const float qy##i = qpos[(size_t)(qbase + i) * 3 + 1]; \
  const float qz##i = qpos[(size_t)(qbase + i) * 3 + 2]; \
  const float qq##i = __fadd_rn(__fadd_rn(__fmul_rn(qx##i, qx##i), __fmul_rn(qy##i, qy##i)), __fmul_rn(qz##i, qz##i));
  FORQ(LOADQ)
#undef LOADQ

  const int sbase = w * 2048;

  // ---- pass 1 (FULL): per-lane min of shifted filter s = kk - 2*dotA ----
#define DECLMN(i) float mn##i = 3.4e38f;
  FORQ(DECLMN)
#undef DECLMN
  {
    const float4* p0 = kp4 + sbase + l;
    float4 c0 = p0[0], c1 = p0[64], c2 = p0[128], c3 = p0[192];
    const float4* nx = p0 + 256;
#define P1Q(i, cc) { \
      const float dA = fmaf(qx##i, (cc).x, fmaf(qy##i, (cc).y, __fmul_rn(qz##i, (cc).z))); \
      const float sF = fmaf(-2.0f, dA, (cc).w); \
      mn##i = fminf(mn##i, sF); }
#define P1_PT(cc, RELOAD) { \
      P1Q(0, cc) P1Q(1, cc) P1Q(2, cc) P1Q(3, cc) \
      P1Q(4, cc) P1Q(5, cc) P1Q(6, cc) P1Q(7, cc) \
      cc = RELOAD; }
    for (int t = 0; t < 8; ++t) {
      P1_PT(c0, nx[0])
      P1_PT(c1, nx[64])
      P1_PT(c2, nx[128])
      P1_PT(c3, nx[192])
      nx += 256;
    }
#undef P1_PT
  }
#define STMN(i) pmins[w][i][l] = mn##i;
  FORQ(STMN)
#undef STMN
  __syncthreads();

  // ---- cutoffs (shifted space): per query, max over 16 groups ----
#define CUTQ(i) float cut##i; { \
    float m = pmins[0][i][l]; \
    m = fminf(m, pmins[1][i][l]); m = fminf(m, pmins[2][i][l]); \
    m = fminf(m, pmins[3][i][l]); m = fminf(m, pmins[4][i][l]); \
    m = fminf(m, pmins[5][i][l]); m = fminf(m, pmins[6][i][l]); \
    m = fminf(m, pmins[7][i][l]); \
    m = fminf(m, __shfl_xor(m, 16, 64)); \
    m = fminf(m, __shfl_xor(m, 32, 64)); \
    m = fmaxf(m, __shfl_xor(m, 1, 64)); \
    m = fmaxf(m, __shfl_xor(m, 2, 64)); \
    m = fmaxf(m, __shfl_xor(m, 4, 64)); \
    m = fmaxf(m, __shfl_xor(m, 8, 64)); \
    cut##i = m + 2e-5f; }
  FORQ(CUTQ)
#undef CUTQ

  // ---- pass 2 (FULL): shifted filter, exact d2 key for survivors ----
#define DECLCNT(i) int cnt##i = 0;
  FORQ(DECLCNT)
#undef DECLCNT
  {
    const float4* p0 = kp4 + sbase + l;
    float4 c0 = p0[0], c1 = p0[64], c2 = p0[128], c3 = p0[192];
    const float4* nx = p0 + 256;
    int p = sbase + l;
#define P2Q(i, cc, pp) { \
      const float dA = fmaf(qx##i, (cc).x, fmaf(qy##i, (cc).y, __fmul_rn(qz##i, (cc).z))); \
      const float sF = fmaf(-2.0f, dA, (cc).w); \
      const bool pred = (sF <= cut##i); \
      const unsigned long long mask = __ballot(pred); \
      if (mask) { \
        if (pred) { \
          const float dotE = __fadd_rn(__fadd_rn(__fmul_rn(qz##i, (cc).z), __fmul_rn(qy##i, (cc).y)), __fmul_rn(qx##i, (cc).x)); \
          const float d2e = __fadd_rn(__fsub_rn(qq##i, __fmul_rn(2.0f, dotE)), (cc).w); \
          unsigned int u = __float_as_uint(d2e); \
          u ^= (unsigned int)((int)u >> 31) | 0x80000000u; \
          const int off = __builtin_amdgcn_mbcnt_hi((unsigned int)(mask >> 32), \
                          __builtin_amdgcn_mbcnt_lo((unsigned int)mask, 0)); \
          const int pos = cnt##i + off; \
          if (pos < 48) cbuf[i][w][pos] = ((unsigned long long)u << 32) | (unsigned int)(pp); \
        } \
        cnt##i += (int)__popcll(mask); \
      } }
#define P2_PT(cc, RELOAD, POFF) { \
      P2Q(0, cc, p + POFF) P2Q(1, cc, p + POFF) P2Q(2, cc, p + POFF) P2Q(3, cc, p + POFF) \
      P2Q(4, cc, p + POFF) P2Q(5, cc, p + POFF) P2Q(6, cc, p + POFF) P2Q(7, cc, p + POFF) \
      cc = RELOAD; }
    for (int t = 0; t < 8; ++t) {
      P2_PT(c0, nx[0], 0)
      P2_PT(c1, nx[64], 64)
      P2_PT(c2, nx[128], 128)
      P2_PT(c3, nx[192], 192)
      nx += 256;
      p += 256;
    }
#undef P2_PT
#undef P2Q
  }
#define STCNT(i) if (l == 0) cnts[i][w] = (cnt##i > 48 ? 48 : cnt##i);
  FORQ(STCNT)
#undef STCNT
  __syncthreads();

  // ---- merge + epilogue: wave w owns query qbase + w ----
  const int qi = w;
  const int q = qbase + qi;
  unsigned long long cand[8];
#pragma unroll
  for (int i = 0; i < 8; ++i) {
    const int cn = cnts[qi][i];
    cand[i] = (l < cn) ? cbuf[qi][i][l] : ~0ull;
  }
  unsigned long long lmin = cand[0]; int lpos = 0;
#pragma unroll
  for (int i = 1; i < 8; ++i) { if (cand[i] < lmin) { lmin = cand[i]; lpos = i; } }
  unsigned long long sel64 = 0;
  for (int r = 0; r < 16; ++r) {
    const unsigned long long m = wavemin_u64(lmin);
    if (l == r) sel64 = m;
    if (lmin == m) {
#pragma unroll
      for (int i = 0; i < 8; ++i) cand[i] = (lpos == i) ? ~0ull : cand[i];
      lmin = cand[0]; lpos = 0;
#pragma unroll
      for (int i = 1; i < 8; ++i) { if (cand[i] < lmin) { lmin = cand[i]; lpos = i; } }
    }
  }
  const int myidx = (int)(sel64 & 0xffffffffull);
  if (l < 16) ((int*)(ws + OFF_IDX))[q * 16 + l] = myidx;

  // scores: j = l&15 owns neighbor j; 4 replicas (l>>4) cover 32 channels
  // each of pe AND ksum (fused, R16/R17 verified).
  const float* qpw = qpos + (size_t)q * 3;
  const float gx = qpw[0], gy = qpw[1], gz = qpw[2];
  const int j = l & 15;
  const int pj = __shfl(myidx, j, 64);
  const float* kpj = kp + (size_t)pj * 3;
  const float rx = gx - kpj[0];
  const float ry = gy - kpj[1];
  const float rz = gz - kpj[2];
  const int i0 = (l >> 4) * 32;
  float pe = 0.f;
  for (int i = i0; i < i0 + 32; ++i) {
    float hh = fmaf(rx, W1[i * 3 + 0], fmaf(ry, W1[i * 3 + 1], fmaf(rz, W1[i * 3 + 2], b1[i])));
    hh = fmaxf(hh, 0.f);
    pe = fmaf(hh, w2s_s[i], pe);
  }
  float ks = 0.f;
  {
    const float4* k4 = (const float4*)(kf + (size_t)b * NPTS * DD + (size_t)pj * DD + i0);
    const float4* c4 = (const float4*)(ck_s + i0);
#pragma unroll
    for (int ii = 0; ii < 8; ++ii) {
      const float4 kv = k4[ii];
      const float4 cv = c4[ii];
      ks = fmaf(kv.x, cv.x, ks);
      ks = fmaf(kv.y, cv.y, ks);
      ks = fmaf(kv.z, cv.z, ks);
      ks = fmaf(kv.w, cv.w, ks);
    }
  }
  pe += __shfl_xor(pe, 16, 64);
  pe += __shfl_xor(pe, 32, 64);
  ks += __shfl_xor(ks, 16, 64);
  ks += __shfl_xor(ks, 32, 64);
  float score = qsum_w - (ks + scl_s[1]) + pe + scl_s[2];
  float mx = score;
  mx = fmaxf(mx, __shfl_xor(mx, 1, 64));
  mx = fmaxf(mx, __shfl_xor(mx, 2, 64));
  mx = fmaxf(mx, __shfl_xor(mx, 4, 64));
  mx = fmaxf(mx, __shfl_xor(mx, 8, 64));
  const float e = expf(score - mx);
  float se = e;
  se += __shfl_xor(se, 1, 64);
  se += __shfl_xor(se, 2, 64);
  se += __shfl_xor(se, 4, 64);
  se += __shfl_xor(se, 8, 64);
  const float attn = e / se;
  if (l < 16) {
    ws[OFF_ATTN + q * 16 + l] = attn;
    atomicAdd(&ws[OFF_COL + b * 16 + l], attn);
  }
}

// ---------- K3: fused gather + out -- R18: 512 threads, 1 query/wave ----------
// Gather: wave w owns query qbase+w (serial chain halved vs 2 queries/wave);
// 8 waves/block doubles resident waves/CU. Per-query FP sequence identical
// to R17 (same lane roles, same fmaf order). Out: rg = tid>>7 in 0..3 covers
// rows rg*2, rg*2+1 -- per-row compute identical (init asum*bvo, ascending-i
// fmaf over WVT).
__global__ __launch_bounds__(512) void k_go(const float* __restrict__ kf,
                                            const float* __restrict__ bv,
                                            const float* __restrict__ ws,
                                            float* __restrict__ out) {
  __shared__ float xg[8 * 128];
  __shared__ float as_s[8];
  const int tid = threadIdx.x;
  const int w = tid >> 6, l = tid & 63;
  const int qbase = (int)blockIdx.x * 8;
  const int b = qbase >> 10;
  const float* kb = kf + (size_t)b * NPTS * DD;

  {
    const int q = qbase + w;
    float a = 0.f;
    int pidx = 0;
    if (l < 16) {
      a = ws[OFF_ATTN + q * 16 + l] / (ws[OFF_COL + b * 16 + l] + EPSF);
      pidx = ((const int*)(ws + OFF_IDX))[q * 16 + l];
    }
    float asum = a;
    asum += __shfl_xor(asum, 1, 64);
    asum += __shfl_xor(asum, 2, 64);
    asum += __shfl_xor(asum, 4, 64);
    asum += __shfl_xor(asum, 8, 64);
    if (l == 0) as_s[w] = asum;
    float acc0 = 0.f, acc1 = 0.f;
#pragma unroll
    for (int jj = 0; jj < 16; ++jj) {
      const float aj = __shfl(a, jj, 64);
      const int pj = __shfl(pidx, jj, 64);
      const float* row = kb + (size_t)pj * DD;
      acc0 = fmaf(aj, row[l], acc0);
      acc1 = fmaf(aj, row[64 + l], acc1);
    }
    xg[w * 128 + l] = acc0;
    xg[w * 128 + 64 + l] = acc1;
  }
  __syncthreads();

  const int o = tid & 127, rg = tid >> 7;  // rg 0..3, rows rg*2, rg*2+1
  const float bvo = bv[o];
  float acc[2];
#pragma unroll
  for (int r = 0; r < 2; ++r) acc[r] = as_s[rg * 2 + r] * bvo;
  for (int i = 0; i < DD; ++i) {
    const float wv = ws[OFF_WVT + i * DD + o];
#pragma unroll
    for (int r = 0; r < 2; ++r) acc[r] = fmaf(wv, xg[(rg * 2 + r) * 128 + i], acc[r]);
  }
#pragma unroll
  for (int r = 0; r < 2; ++r) out[(size_t)(qbase + rg * 2 + r) * DD + o] = acc[r];
}

extern "C" void kernel_launch(void* const* d_in, const int* in_sizes, int n_in,
                              void* d_out, int out_size, void* d_ws, size_t ws_size,
                              hipStream_t stream) {
  const float* qf   = (const float*)d_in[0];
  const float* kf   = (const float*)d_in[1];
  const float* qpos = (const float*)d_in[2];
  const float* kpos = (const float*)d_in[3];
  const float* Wq   = (const float*)d_in[4];
  const float* bq   = (const float*)d_in[5];
  const float* Wk   = (const float*)d_in[6];
  const float* bk   = (const float*)d_in[7];
  const float* Wv   = (const float*)d_in[8];
  const float* bv   = (const float*)d_in[9];
  const float* W1   = (const float*)d_in[10];
  const float* b1   = (const float*)d_in[11];
  const float* W2   = (const float*)d_in[12];
  const float* b2   = (const float*)d_in[13];
  float* ws  = (float*)d_ws;
  float* out = (float*)d_out;

  k_pre<<<256, 256, 0, stream>>>(kpos, Wv, Wq, bq, Wk, bk, W2, b2, ws);
  k_knn<<<512, 512, 0, stream>>>(qf, kf, qpos, kpos, W1, b1, ws);
  k_go<<<512, 512, 0, stream>>>(kf, bv, ws, out);
}